// Round 2
// baseline (598.153 us; speedup 1.0000x reference)
//
#include <hip/hip_runtime.h>
#include <hip/hip_bf16.h>

// Problem constants (fixed by setup_inputs)
#define T_TOK 2048
#define DDIM  2048
#define IDIM  2816
#define NE    8
#define NPAIR (T_TOK*2)      // 4096 (token, k) pairs
#define GU_N  (2*IDIM)       // 5632

typedef __bf16  bf16x8 __attribute__((ext_vector_type(8)));
typedef float   f32x4  __attribute__((ext_vector_type(4)));
typedef int     int4v  __attribute__((ext_vector_type(4)));
typedef unsigned int uint4v __attribute__((ext_vector_type(4)));

// ws layout (bytes)
#define OFF_A   (64*1024)
#define OFF_GU  (OFF_A  + (size_t)NPAIR*DDIM*2)   // A_all: 16 MB bf16 (pre-swizzled)
#define OFF_H   (OFF_GU + (size_t)NPAIR*GU_N*2)   // gate_up: 46 MB bf16 (linear)
#define OFF_YP  (OFF_H  + (size_t)NPAIR*IDIM*2)   // h: 23 MB bf16 (pre-swizzled)
// yp: 32 MB f32 after that; total ~119 MB

__device__ __forceinline__ unsigned short f2bf(float f) {
    __hip_bfloat16 h = __float2bfloat16(f);
    return __builtin_bit_cast(unsigned short, h);
}
__device__ __forceinline__ float bf2f(unsigned short u) {
    unsigned int x = ((unsigned int)u) << 16;
    return __builtin_bit_cast(float, x);
}
__device__ __forceinline__ unsigned int pack2bf(float lo, float hi) {
    return ((unsigned int)f2bf(hi) << 16) | (unsigned int)f2bf(lo);
}
// async global->LDS, 16B per lane; LDS dest must be wave-uniform-base + lane*16
__device__ __forceinline__ void gload_lds16(const void* g, void* l) {
    __builtin_amdgcn_global_load_lds(
        (const __attribute__((address_space(1))) void*)g,
        (__attribute__((address_space(3))) void*)l, 16, 0, 0);
}

// ---------------- routing: stable compaction of 4096 pairs by expert ---------
// meta: [0..7]=cnt, [8..15]=off (exclusive prefix), [64..64+4095]=list (pair idx)
__global__ void route_kernel(const int* __restrict__ ids, int* __restrict__ meta) {
    __shared__ int histL[NE][256];
    __shared__ int totals[NE];
    __shared__ int offsS[NE];
    const int tid = threadIdx.x;
    for (int e = 0; e < NE; ++e) histL[e][tid] = 0;
    for (int j = 0; j < 16; ++j) {
        int id = ids[tid*16 + j];
        histL[id][tid]++;
    }
    __syncthreads();
    if (tid < NE) {
        int run = 0;
        for (int i = 0; i < 256; ++i) { int v = histL[tid][i]; histL[tid][i] = run; run += v; }
        totals[tid] = run;
    }
    __syncthreads();
    if (tid == 0) {
        int run = 0;
        for (int e = 0; e < NE; ++e) {
            offsS[e] = run;
            meta[e] = totals[e];
            meta[8+e] = run;
            run += totals[e];
        }
    }
    __syncthreads();
    for (int j = 0; j < 16; ++j) {
        int p = tid*16 + j;
        int id = ids[p];
        int local = histL[id][tid];
        histL[id][tid] = local + 1;
        meta[64 + offsS[id] + local] = p;
    }
}

// ---------------- gather: x rows -> compact PRE-SWIZZLED bf16 A matrix -------
// logical col-byte cb of row r stored at (cb&~127) | ((cb&127) ^ ((r&7)<<4))
__global__ void gather_kernel(const float* __restrict__ x, const int* __restrict__ meta,
                              unsigned short* __restrict__ Aall) {
    const int r = blockIdx.x;
    const int p = meta[64 + r];
    const int t = p >> 1;
    const int c = threadIdx.x * 8;
    const float4* src = (const float4*)(x + (size_t)t*DDIM + c);
    float4 f0 = src[0], f1 = src[1];
    unsigned short o[8];
    o[0]=f2bf(f0.x); o[1]=f2bf(f0.y); o[2]=f2bf(f0.z); o[3]=f2bf(f0.w);
    o[4]=f2bf(f1.x); o[5]=f2bf(f1.y); o[6]=f2bf(f1.z); o[7]=f2bf(f1.w);
    int cb  = c * 2;
    int cbs = (cb & ~127) | ((cb & 127) ^ ((r & 7) << 4));
    *(uint4v*)((char*)Aall + (size_t)r*(DDIM*2) + cbs) = *(uint4v*)o;
}

// ============ pipelined dequant-GEMM macros (shared by gemm1/gemm2) ==========
// 512 threads/block, 256x128 output tile, K-step 64.
// B staging: arow = tid>>2 (128 rows), aq = tid&3 (quarter-row: 8 packed ints)
// LOADB: issue packed-B + scale/zp loads for K-tile KT (no forced wait; zp raw)
#define LOADB(PK, SS, ZZ, KT)  do {                                        \
    const int4v* _bg = (const int4v*)(bgp + (KT)*32);                      \
    PK##0 = _bg[0]; PK##1 = _bg[1];                                        \
    int _g = (KT) >> 1;                                                    \
    SS = sp[_g]; ZZ = zp[_g];                                              \
} while (0)

// ISSUE_A: async-copy A K-slab KT into As[SEL] (linear copy of pre-swizzled rows)
// 8 waves x 32 rows x 128B = 256 rows
#define ISSUE_A(SEL, KT) do {                                              \
    _Pragma("unroll")                                                      \
    for (int _i = 0; _i < 4; ++_i)                                         \
        gload_lds16(a_src[_i] + (size_t)(KT)*128,                          \
                    (char*)&As[SEL][0] + wv*4096 + _i*1024 + lane*16);     \
} while (0)

// DEQ: int4 nibbles -> packed bf16 pairs (packed values < 256: hi needs no mask)
#define DEQ1(PKQ, SS, CC, BWP, QO) do {                                    \
    _Pragma("unroll")                                                      \
    for (int _j = 0; _j < 4; ++_j) {                                       \
        int _v = PKQ[_j];                                                  \
        float _lo = (float)(_v & 15);                                      \
        float _hi = (float)(_v >> 4);                                      \
        BWP[(QO)*4 + _j] = pack2bf(fmaf(_lo, SS, CC), fmaf(_hi, SS, CC));  \
    }                                                                      \
} while (0)
#define DEQ(PK, SS, ZZ, BWP) do {                                         \
    float _s = SS, _c = -(ZZ)*(SS);                                       \
    DEQ1(PK##0, _s, _c, BWP, 0); DEQ1(PK##1, _s, _c, BWP, 1);             \
} while (0)

#define WRITE_BS(BWP) do {                                                 \
    _Pragma("unroll")                                                      \
    for (int _q = 0; _q < 2; ++_q) {                                       \
        int _cb  = aq*32 + _q*16;                                          \
        int _cbs = _cb ^ swzB;                                             \
        *(uint4v*)(&Bs[arow*64 + (_cbs >> 1)]) = *(uint4v*)(&BWP[_q*4]);   \
    }                                                                      \
} while (0)

// MFMA_STEP: ds_read frags (A xor uses global-row parity base7+row) and accumulate
// 8 waves: wm = (wv>>1)*64 in [0,256), wn = (wv&1)*64 in [0,128)
#define MFMA_STEP(SEL) do {                                                \
    _Pragma("unroll")                                                      \
    for (int _kk = 0; _kk < 2; ++_kk) {                                    \
        bf16x8 _af[4], _bf[4];                                             \
        const int _kbyte = _kk*64 + lk*16;                                 \
        _Pragma("unroll")                                                  \
        for (int _mi = 0; _mi < 4; ++_mi) {                                \
            int _row = wm + _mi*16 + lr;                                   \
            int _b = _kbyte ^ (((_row + base7) & 7) << 4);                 \
            _af[_mi] = *(const bf16x8*)(&As[SEL][_row*64 + (_b >> 1)]);    \
        }                                                                  \
        _Pragma("unroll")                                                  \
        for (int _nj = 0; _nj < 4; ++_nj) {                                \
            int _row = wn + _nj*16 + lr;                                   \
            int _b = _kbyte ^ ((_row & 7) << 4);                           \
            _bf[_nj] = *(const bf16x8*)(&Bs[_row*64 + (_b >> 1)]);         \
        }                                                                  \
        _Pragma("unroll")                                                  \
        for (int _mi = 0; _mi < 4; ++_mi)                                  \
            _Pragma("unroll")                                              \
            for (int _nj = 0; _nj < 4; ++_nj)                              \
                acc[_mi][_nj] = __builtin_amdgcn_mfma_f32_16x16x32_bf16(   \
                    _af[_mi], _bf[_nj], acc[_mi][_nj], 0, 0, 0);           \
    }                                                                      \
} while (0)

// One K-step: barrier1; issue t+1 (A async->LDS, B->regs); dequant+commit t;
// barrier2 (drain covered by dequant); MFMA t.  (Proven-correct structure;
// R1's raw-barrier variant regressed: compiler fences killed overlap.)
#define STEP(T, SELC, SELN, PKC, sC, zC, PKN, sN, zN) do {                 \
    if ((T) > 0) __syncthreads();                                          \
    int _ktn = (T)+1 < NT ? (T)+1 : NT-1;                                  \
    ISSUE_A(SELN, _ktn);                                                   \
    LOADB(PKN, sN, zN, _ktn);                                              \
    unsigned int _bw[8];                                                   \
    DEQ(PKC, sC, zC, _bw);                                                 \
    WRITE_BS(_bw);                                                         \
    __syncthreads();                                                       \
    MFMA_STEP(SELC);                                                       \
} while (0)

// ---------------- GEMM1: A[4096,2048]bf16 x W13[e]^T (int4 dequant) ----------
// 256x128 tile, 512 threads, 80KB LDS -> 2 blocks/CU (16 waves/CU)
__launch_bounds__(512, 4)
__global__ void gemm1_kernel(const unsigned short* __restrict__ Aall,
                             const int* __restrict__ wp,
                             const float* __restrict__ wsc,
                             const float* __restrict__ wzp,
                             const int* __restrict__ meta,
                             unsigned short* __restrict__ gu) {
    const int e   = blockIdx.z;
    const int cnt = meta[e];
    const int m0  = blockIdx.y * 256;
    if (m0 >= cnt) return;
    const int off = meta[8 + e];
    const int n0  = blockIdx.x * 128;
    const int tid = threadIdx.x;

    __shared__ unsigned short As[2][256*64];   // 64 KB
    __shared__ unsigned short Bs[128*64];      // 16 KB

    f32x4 acc[4][4];
#pragma unroll
    for (int i = 0; i < 4; ++i)
#pragma unroll
        for (int j = 0; j < 4; ++j) acc[i][j] = (f32x4)0.0f;

    // B staging mapping (reg-staged + dequant): 4 threads per B-row
    const int arow  = tid >> 2;
    const int aq    = tid & 3;
    const int gbrow = n0 + arow;
    const int* bgp  = wp  + ((size_t)e*GU_N + gbrow)*(DDIM/2) + aq*8;
    const float* sp = wsc + ((size_t)e*GU_N + gbrow)*(DDIM/128);
    const float* zp = wzp + ((size_t)e*GU_N + gbrow)*(DDIM/128);
    const int swzB  = (arow & 7) << 4;

    // A async-copy mapping: 8 waves x 32 rows
    const int lane = tid & 63;
    const int wv   = tid >> 6;
    const char* a_src[4];
#pragma unroll
    for (int i = 0; i < 4; ++i) {
        int lrow  = wv*32 + i*8 + (lane >> 3);
        int garow = off + m0 + lrow; if (garow > NPAIR-1) garow = NPAIR-1;
        a_src[i] = (const char*)Aall + (size_t)garow*(DDIM*2) + (lane & 7)*16;
    }
    const int base7 = (off + m0) & 7;

    const int wm = (wv >> 1) * 64, wn = (wv & 1) * 64;
    const int lr = lane & 15, lk = lane >> 4;

    const int NT = DDIM/64;   // 32 (even)
    int4v pkX0, pkX1, pkY0, pkY1;
    float sX, zX, sY, zY;

    ISSUE_A(0, 0);
    LOADB(pkX, sX, zX, 0);
    for (int kt = 0; kt < NT; kt += 2) {
        STEP(kt,   0, 1, pkX, sX, zX, pkY, sY, zY);
        STEP(kt+1, 1, 0, pkY, sY, zY, pkX, sX, zX);
    }

    // epilogue: C[m][n] lane map col=lane&15, row=(lane>>4)*4+reg (m89)
#pragma unroll
    for (int mi = 0; mi < 4; ++mi)
#pragma unroll
        for (int nj = 0; nj < 4; ++nj) {
            f32x4 v = acc[mi][nj];
            int col = n0 + wn + nj*16 + lr;
#pragma unroll
            for (int r = 0; r < 4; ++r) {
                int row = wm + mi*16 + lk*4 + r;
                if (m0 + row < cnt)
                    gu[(size_t)(off + m0 + row)*GU_N + col] = f2bf(v[r]);
            }
        }
}

// ---------------- activation: h = silu(g)*u, written PRE-SWIZZLED ------------
__global__ void act_kernel(const unsigned short* __restrict__ gu,
                           unsigned short* __restrict__ h) {
    const int r = blockIdx.x;
    for (int c = threadIdx.x; c < IDIM/8; c += 256) {
        uint4v g8 = *(const uint4v*)(&gu[(size_t)r*GU_N + c*8]);
        uint4v u8 = *(const uint4v*)(&gu[(size_t)r*GU_N + IDIM + c*8]);
        const unsigned short* gp = (const unsigned short*)&g8;
        const unsigned short* up = (const unsigned short*)&u8;
        unsigned short o[8];
#pragma unroll
        for (int j = 0; j < 8; ++j) {
            float g = bf2f(gp[j]), u = bf2f(up[j]);
            float sg = g / (1.0f + __expf(-g));
            o[j] = f2bf(sg * u);
        }
        int cb  = c * 16;
        int cbs = (cb & ~127) | ((cb & 127) ^ ((r & 7) << 4));
        *(uint4v*)((char*)h + (size_t)r*(IDIM*2) + cbs) = *(uint4v*)o;
    }
}

// ---------------- GEMM2: h[4096,2816]bf16 x W2[e]^T (int4 dequant) -----------
__launch_bounds__(512, 4)
__global__ void gemm2_kernel(const unsigned short* __restrict__ h,
                             const int* __restrict__ wp,
                             const float* __restrict__ wsc,
                             const float* __restrict__ wzp,
                             const float* __restrict__ tw,
                             const int* __restrict__ meta,
                             float* __restrict__ yp) {
    const int e   = blockIdx.z;
    const int cnt = meta[e];
    const int m0  = blockIdx.y * 256;
    if (m0 >= cnt) return;
    const int off = meta[8 + e];
    const int n0  = blockIdx.x * 128;
    const int tid = threadIdx.x;

    __shared__ unsigned short As[2][256*64];   // 64 KB
    __shared__ unsigned short Bs[128*64];      // 16 KB

    f32x4 acc[4][4];
#pragma unroll
    for (int i = 0; i < 4; ++i)
#pragma unroll
        for (int j = 0; j < 4; ++j) acc[i][j] = (f32x4)0.0f;

    const int arow  = tid >> 2;
    const int aq    = tid & 3;
    const int gbrow = n0 + arow;
    const int* bgp  = wp  + ((size_t)e*DDIM + gbrow)*(IDIM/2) + aq*8;
    const float* sp = wsc + ((size_t)e*DDIM + gbrow)*(IDIM/128);
    const float* zp = wzp + ((size_t)e*DDIM + gbrow)*(IDIM/128);
    const int swzB  = (arow & 7) << 4;

    const int lane = tid & 63;
    const int wv   = tid >> 6;
    const char* a_src[4];
#pragma unroll
    for (int i = 0; i < 4; ++i) {
        int lrow  = wv*32 + i*8 + (lane >> 3);
        int garow = off + m0 + lrow; if (garow > NPAIR-1) garow = NPAIR-1;
        a_src[i] = (const char*)h + (size_t)garow*(IDIM*2) + (lane & 7)*16;
    }
    const int base7 = (off + m0) & 7;

    const int wm = (wv >> 1) * 64, wn = (wv & 1) * 64;
    const int lr = lane & 15, lk = lane >> 4;

    const int NT = IDIM/64;   // 44 (even)
    int4v pkX0, pkX1, pkY0, pkY1;
    float sX, zX, sY, zY;

    ISSUE_A(0, 0);
    LOADB(pkX, sX, zX, 0);
    for (int kt = 0; kt < NT; kt += 2) {
        STEP(kt,   0, 1, pkX, sX, zX, pkY, sY, zY);
        STEP(kt+1, 1, 0, pkY, sY, zY, pkX, sX, zX);
    }

#pragma unroll
    for (int mi = 0; mi < 4; ++mi)
#pragma unroll
        for (int nj = 0; nj < 4; ++nj) {
            f32x4 v = acc[mi][nj];
            int col = n0 + wn + nj*16 + lr;
#pragma unroll
            for (int r = 0; r < 4; ++r) {
                int row = wm + mi*16 + lk*4 + r;
                if (m0 + row < cnt) {
                    int p = meta[64 + off + m0 + row];
                    float w = tw[p];
                    yp[(size_t)p*DDIM + col] = v[r] * w;
                }
            }
        }
}

// ---------------- combine: out[t] = yp[2t] + yp[2t+1] ------------------------
__global__ void combine_kernel(const float* __restrict__ yp, float* __restrict__ out) {
    const int i = blockIdx.x * 256 + threadIdx.x;      // float4 index
    const int t = i >> 9, d = i & 511;
    const f32x4* a = (const f32x4*)yp;
    f32x4 va = a[(size_t)(t*2)*512 + d];
    f32x4 vb = a[(size_t)(t*2+1)*512 + d];
    ((f32x4*)out)[i] = va + vb;
}

extern "C" void kernel_launch(void* const* d_in, const int* in_sizes, int n_in,
                              void* d_out, int out_size, void* d_ws, size_t ws_size,
                              hipStream_t stream) {
    const float* x    = (const float*)d_in[0];
    const int*   ids  = (const int*)d_in[1];
    const float* tw   = (const float*)d_in[2];
    const int*   w13p = (const int*)d_in[3];
    const float* w13s = (const float*)d_in[4];
    const float* w13z = (const float*)d_in[5];
    const int*   w2p  = (const int*)d_in[6];
    const float* w2s  = (const float*)d_in[7];
    const float* w2z  = (const float*)d_in[8];
    float* out = (float*)d_out;

    char* ws = (char*)d_ws;
    int* meta = (int*)ws;
    unsigned short* Aall = (unsigned short*)(ws + OFF_A);
    unsigned short* gu   = (unsigned short*)(ws + OFF_GU);
    unsigned short* h    = (unsigned short*)(ws + OFF_H);
    float* yp            = (float*)(ws + OFF_YP);

    route_kernel<<<1, 256, 0, stream>>>(ids, meta);
    gather_kernel<<<NPAIR, 256, 0, stream>>>(x, meta, Aall);
    gemm1_kernel<<<dim3(GU_N/128, NPAIR/256, NE), 512, 0, stream>>>(Aall, w13p, w13s, w13z, meta, gu);
    act_kernel<<<NPAIR, 256, 0, stream>>>(gu, h);
    gemm2_kernel<<<dim3(DDIM/128, NPAIR/256, NE), 512, 0, stream>>>(h, w2p, w2s, w2z, tw, meta, yp);
    combine_kernel<<<(T_TOK*DDIM/4)/256, 256, 0, stream>>>(yp, out);
}

// Round 3
// 488.540 us; speedup vs baseline: 1.2244x; 1.2244x over previous
//
#include <hip/hip_runtime.h>
#include <hip/hip_bf16.h>

// Problem constants (fixed by setup_inputs)
#define T_TOK 2048
#define DDIM  2048
#define IDIM  2816
#define NE    8
#define NPAIR (T_TOK*2)      // 4096 (token, k) pairs
#define GU_N  (2*IDIM)       // 5632

typedef __bf16  bf16x8 __attribute__((ext_vector_type(8)));
typedef float   f32x4  __attribute__((ext_vector_type(4)));
typedef int     int4v  __attribute__((ext_vector_type(4)));
typedef unsigned int uint4v __attribute__((ext_vector_type(4)));

// ws layout (bytes)
#define OFF_A   (64*1024)
#define OFF_GU  (OFF_A  + (size_t)NPAIR*DDIM*2)   // A_all: 16 MB bf16 (pre-swizzled)
#define OFF_H   (OFF_GU + (size_t)NPAIR*GU_N*2)   // gate_up: 46 MB bf16 (linear)
#define OFF_YP  (OFF_H  + (size_t)NPAIR*IDIM*2)   // h: 23 MB bf16 (pre-swizzled)
// yp: 32 MB f32 after that; total ~119 MB

__device__ __forceinline__ unsigned short f2bf(float f) {
    __hip_bfloat16 h = __float2bfloat16(f);
    return __builtin_bit_cast(unsigned short, h);
}
__device__ __forceinline__ float bf2f(unsigned short u) {
    unsigned int x = ((unsigned int)u) << 16;
    return __builtin_bit_cast(float, x);
}
__device__ __forceinline__ unsigned int pack2bf(float lo, float hi) {
    return ((unsigned int)f2bf(hi) << 16) | (unsigned int)f2bf(lo);
}
// async global->LDS, 16B per lane; LDS dest must be wave-uniform-base + lane*16
__device__ __forceinline__ void gload_lds16(const void* g, void* l) {
    __builtin_amdgcn_global_load_lds(
        (const __attribute__((address_space(1))) void*)g,
        (__attribute__((address_space(3))) void*)l, 16, 0, 0);
}

// ---------------- routing: stable compaction of 4096 pairs by expert ---------
// meta: [0..7]=cnt, [8..15]=off (exclusive prefix), [64..64+4095]=list (pair idx)
__global__ void route_kernel(const int* __restrict__ ids, int* __restrict__ meta) {
    __shared__ int histL[NE][256];
    __shared__ int totals[NE];
    __shared__ int offsS[NE];
    const int tid = threadIdx.x;
    for (int e = 0; e < NE; ++e) histL[e][tid] = 0;
    for (int j = 0; j < 16; ++j) {
        int id = ids[tid*16 + j];
        histL[id][tid]++;
    }
    __syncthreads();
    if (tid < NE) {
        int run = 0;
        for (int i = 0; i < 256; ++i) { int v = histL[tid][i]; histL[tid][i] = run; run += v; }
        totals[tid] = run;
    }
    __syncthreads();
    if (tid == 0) {
        int run = 0;
        for (int e = 0; e < NE; ++e) {
            offsS[e] = run;
            meta[e] = totals[e];
            meta[8+e] = run;
            run += totals[e];
        }
    }
    __syncthreads();
    for (int j = 0; j < 16; ++j) {
        int p = tid*16 + j;
        int id = ids[p];
        int local = histL[id][tid];
        histL[id][tid] = local + 1;
        meta[64 + offsS[id] + local] = p;
    }
}

// ---------------- gather: x rows -> compact PRE-SWIZZLED bf16 A matrix -------
// logical col-byte cb of row r stored at (cb&~127) | ((cb&127) ^ ((r&7)<<4))
__global__ void gather_kernel(const float* __restrict__ x, const int* __restrict__ meta,
                              unsigned short* __restrict__ Aall) {
    const int r = blockIdx.x;
    const int p = meta[64 + r];
    const int t = p >> 1;
    const int c = threadIdx.x * 8;
    const float4* src = (const float4*)(x + (size_t)t*DDIM + c);
    float4 f0 = src[0], f1 = src[1];
    unsigned short o[8];
    o[0]=f2bf(f0.x); o[1]=f2bf(f0.y); o[2]=f2bf(f0.z); o[3]=f2bf(f0.w);
    o[4]=f2bf(f1.x); o[5]=f2bf(f1.y); o[6]=f2bf(f1.z); o[7]=f2bf(f1.w);
    int cb  = c * 2;
    int cbs = (cb & ~127) | ((cb & 127) ^ ((r & 7) << 4));
    *(uint4v*)((char*)Aall + (size_t)r*(DDIM*2) + cbs) = *(uint4v*)o;
}

// ============ pipelined dequant-GEMM macros (shared by gemm1/gemm2) ==========
// 256 threads/block, 128x128 output tile, K-step 64. (R0 proven shape.)
// LOADB: issue packed-B + scale/zp loads for K-tile KT (no forced wait; zp raw)
#define LOADB(PK, SS, ZZ, KT)  do {                                        \
    const int4v* _bg = (const int4v*)(bgp + (KT)*32);                      \
    PK##0 = _bg[0]; PK##1 = _bg[1]; PK##2 = _bg[2]; PK##3 = _bg[3];        \
    int _g = (KT) >> 1;                                                    \
    SS = sp[_g]; ZZ = zp[_g];                                              \
} while (0)

// ISSUE_A: async-copy A K-slab KT into As[SEL] (linear copy of pre-swizzled rows)
#define ISSUE_A(SEL, KT) do {                                              \
    _Pragma("unroll")                                                      \
    for (int _i = 0; _i < 4; ++_i)                                         \
        gload_lds16(a_src[_i] + (size_t)(KT)*128,                          \
                    (char*)&As[SEL][0] + wv*4096 + _i*1024 + lane*16);     \
} while (0)

// DEQ: int4 nibbles -> packed bf16 pairs (packed values < 256: hi needs no mask)
#define DEQ1(PKQ, SS, CC, BWP, QO) do {                                    \
    _Pragma("unroll")                                                      \
    for (int _j = 0; _j < 4; ++_j) {                                       \
        int _v = PKQ[_j];                                                  \
        float _lo = (float)(_v & 15);                                      \
        float _hi = (float)(_v >> 4);                                      \
        BWP[(QO)*4 + _j] = pack2bf(fmaf(_lo, SS, CC), fmaf(_hi, SS, CC));  \
    }                                                                      \
} while (0)
#define DEQ(PK, SS, ZZ, BWP) do {                                         \
    float _s = SS, _c = -(ZZ)*(SS);                                       \
    DEQ1(PK##0, _s, _c, BWP, 0); DEQ1(PK##1, _s, _c, BWP, 1);             \
    DEQ1(PK##2, _s, _c, BWP, 2); DEQ1(PK##3, _s, _c, BWP, 3);             \
} while (0)

#define WRITE_BS(BWP, BSEL) do {                                           \
    _Pragma("unroll")                                                      \
    for (int _q = 0; _q < 4; ++_q) {                                       \
        int _cb  = ahalf*64 + _q*16;                                       \
        int _cbs = _cb ^ swzB;                                             \
        *(uint4v*)(&Bs[BSEL][arow*64 + (_cbs >> 1)]) = *(uint4v*)(&BWP[_q*4]); \
    }                                                                      \
} while (0)

// MFMA_STEP: ds_read frags (A xor uses global-row parity base7+row) and accumulate
#define MFMA_STEP(ASEL, BSEL) do {                                         \
    _Pragma("unroll")                                                      \
    for (int _kk = 0; _kk < 2; ++_kk) {                                    \
        bf16x8 _af[4], _bf[4];                                             \
        const int _kbyte = _kk*64 + lk*16;                                 \
        _Pragma("unroll")                                                  \
        for (int _mi = 0; _mi < 4; ++_mi) {                                \
            int _row = wm + _mi*16 + lr;                                   \
            int _b = _kbyte ^ (((_row + base7) & 7) << 4);                 \
            _af[_mi] = *(const bf16x8*)(&As[ASEL][_row*64 + (_b >> 1)]);   \
        }                                                                  \
        _Pragma("unroll")                                                  \
        for (int _nj = 0; _nj < 4; ++_nj) {                                \
            int _row = wn + _nj*16 + lr;                                   \
            int _b = _kbyte ^ ((_row & 7) << 4);                           \
            _bf[_nj] = *(const bf16x8*)(&Bs[BSEL][_row*64 + (_b >> 1)]);   \
        }                                                                  \
        _Pragma("unroll")                                                  \
        for (int _mi = 0; _mi < 4; ++_mi)                                  \
            _Pragma("unroll")                                              \
            for (int _nj = 0; _nj < 4; ++_nj)                              \
                acc[_mi][_nj] = __builtin_amdgcn_mfma_f32_16x16x32_bf16(   \
                    _af[_mi], _bf[_nj], acc[_mi][_nj], 0, 0, 0);           \
    }                                                                      \
} while (0)

// Single-sync K-step (Bs double-buffered):
//   DEQ(t)->Bs[t&1] ; __syncthreads ; ISSUE_A(t+1)+LOADB(t+1) ; MFMA(t)
// The sole barrier per step (a) publishes Bs[t&1], (b) drains A(t) whose loads
// are a FULL STEP old (issued after the previous sync), (c) protects all LDS
// buffer reuse (distance >= 1 barrier for every write->read / read->write pair).
// Prefetch issued AFTER the sync is never force-drained young — the per-step
// latency exposure that capped R0 at MfmaUtil 19% is gone. Plain __syncthreads
// only (R1 showed asm fences defeat the scheduler).
#define STEP1(T, AS_CUR, AS_NXT, PKC, sC, zC, PKN, sN, zN) do {            \
    unsigned int _bw[16];                                                  \
    DEQ(PKC, sC, zC, _bw);                                                 \
    WRITE_BS(_bw, (T) & 1);                                                \
    __syncthreads();                                                       \
    int _ktn = (T)+1 < NT ? (T)+1 : NT-1;                                  \
    ISSUE_A(AS_NXT, _ktn);                                                 \
    LOADB(PKN, sN, zN, _ktn);                                              \
    MFMA_STEP(AS_CUR, (T) & 1);                                            \
} while (0)

// ---------------- GEMM1: A[4096,2048]bf16 x W13[e]^T (int4 dequant) ----------
// 128x128 tile, 256 threads, 64KB LDS -> 2 blocks/CU. Loose launch bounds:
// R2 proved tight bounds (128-reg cap) spill the 64-reg accumulator to scratch.
__launch_bounds__(256, 2)
__global__ void gemm1_kernel(const unsigned short* __restrict__ Aall,
                             const int* __restrict__ wp,
                             const float* __restrict__ wsc,
                             const float* __restrict__ wzp,
                             const int* __restrict__ meta,
                             unsigned short* __restrict__ gu) {
    const int e   = blockIdx.z;
    const int cnt = meta[e];
    const int m0  = blockIdx.y * 128;
    if (m0 >= cnt) return;
    const int off = meta[8 + e];
    const int n0  = blockIdx.x * 128;
    const int tid = threadIdx.x;

    __shared__ unsigned short As[2][128*64];   // 32 KB
    __shared__ unsigned short Bs[2][128*64];   // 32 KB

    f32x4 acc[4][4];
#pragma unroll
    for (int i = 0; i < 4; ++i)
#pragma unroll
        for (int j = 0; j < 4; ++j) acc[i][j] = (f32x4)0.0f;

    // B staging mapping (reg-staged + dequant)
    const int arow  = tid >> 1;
    const int ahalf = tid & 1;
    const int gbrow = n0 + arow;
    const int* bgp  = wp  + ((size_t)e*GU_N + gbrow)*(DDIM/2) + ahalf*16;
    const float* sp = wsc + ((size_t)e*GU_N + gbrow)*(DDIM/128);
    const float* zp = wzp + ((size_t)e*GU_N + gbrow)*(DDIM/128);
    const int swzB  = (arow & 7) << 4;

    // A async-copy mapping
    const int lane = tid & 63;
    const int wv   = tid >> 6;
    const char* a_src[4];
#pragma unroll
    for (int i = 0; i < 4; ++i) {
        int lrow  = wv*32 + i*8 + (lane >> 3);
        int garow = off + m0 + lrow; if (garow > NPAIR-1) garow = NPAIR-1;
        a_src[i] = (const char*)Aall + (size_t)garow*(DDIM*2) + (lane & 7)*16;
    }
    const int base7 = (off + m0) & 7;

    const int wm = (wv >> 1) * 64, wn = (wv & 1) * 64;
    const int lr = lane & 15, lk = lane >> 4;

    const int NT = DDIM/64;   // 32 (even)
    int4v pkX0, pkX1, pkX2, pkX3, pkY0, pkY1, pkY2, pkY3;
    float sX, zX, sY, zY;

    ISSUE_A(0, 0);
    LOADB(pkX, sX, zX, 0);
    for (int kt = 0; kt < NT; kt += 2) {
        STEP1(kt,   0, 1, pkX, sX, zX, pkY, sY, zY);
        STEP1(kt+1, 1, 0, pkY, sY, zY, pkX, sX, zX);
    }
    __syncthreads();   // drain trailing (clamped) prefetch before epilogue/endpgm

    // epilogue: C[m][n] lane map col=lane&15, row=(lane>>4)*4+reg (m89)
#pragma unroll
    for (int mi = 0; mi < 4; ++mi)
#pragma unroll
        for (int nj = 0; nj < 4; ++nj) {
            f32x4 v = acc[mi][nj];
            int col = n0 + wn + nj*16 + lr;
#pragma unroll
            for (int r = 0; r < 4; ++r) {
                int row = wm + mi*16 + lk*4 + r;
                if (m0 + row < cnt)
                    gu[(size_t)(off + m0 + row)*GU_N + col] = f2bf(v[r]);
            }
        }
}

// ---------------- activation: h = silu(g)*u, written PRE-SWIZZLED ------------
__global__ void act_kernel(const unsigned short* __restrict__ gu,
                           unsigned short* __restrict__ h) {
    const int r = blockIdx.x;
    for (int c = threadIdx.x; c < IDIM/8; c += 256) {
        uint4v g8 = *(const uint4v*)(&gu[(size_t)r*GU_N + c*8]);
        uint4v u8 = *(const uint4v*)(&gu[(size_t)r*GU_N + IDIM + c*8]);
        const unsigned short* gp = (const unsigned short*)&g8;
        const unsigned short* up = (const unsigned short*)&u8;
        unsigned short o[8];
#pragma unroll
        for (int j = 0; j < 8; ++j) {
            float g = bf2f(gp[j]), u = bf2f(up[j]);
            float sg = g / (1.0f + __expf(-g));
            o[j] = f2bf(sg * u);
        }
        int cb  = c * 16;
        int cbs = (cb & ~127) | ((cb & 127) ^ ((r & 7) << 4));
        *(uint4v*)((char*)h + (size_t)r*(IDIM*2) + cbs) = *(uint4v*)o;
    }
}

// ---------------- GEMM2: h[4096,2816]bf16 x W2[e]^T (int4 dequant) -----------
__launch_bounds__(256, 2)
__global__ void gemm2_kernel(const unsigned short* __restrict__ h,
                             const int* __restrict__ wp,
                             const float* __restrict__ wsc,
                             const float* __restrict__ wzp,
                             const float* __restrict__ tw,
                             const int* __restrict__ meta,
                             float* __restrict__ yp) {
    const int e   = blockIdx.z;
    const int cnt = meta[e];
    const int m0  = blockIdx.y * 128;
    if (m0 >= cnt) return;
    const int off = meta[8 + e];
    const int n0  = blockIdx.x * 128;
    const int tid = threadIdx.x;

    __shared__ unsigned short As[2][128*64];   // 32 KB
    __shared__ unsigned short Bs[2][128*64];   // 32 KB

    f32x4 acc[4][4];
#pragma unroll
    for (int i = 0; i < 4; ++i)
#pragma unroll
        for (int j = 0; j < 4; ++j) acc[i][j] = (f32x4)0.0f;

    const int arow  = tid >> 1;
    const int ahalf = tid & 1;
    const int gbrow = n0 + arow;
    const int* bgp  = wp  + ((size_t)e*DDIM + gbrow)*(IDIM/2) + ahalf*16;
    const float* sp = wsc + ((size_t)e*DDIM + gbrow)*(IDIM/128);
    const float* zp = wzp + ((size_t)e*DDIM + gbrow)*(IDIM/128);
    const int swzB  = (arow & 7) << 4;

    const int lane = tid & 63;
    const int wv   = tid >> 6;
    const char* a_src[4];
#pragma unroll
    for (int i = 0; i < 4; ++i) {
        int lrow  = wv*32 + i*8 + (lane >> 3);
        int garow = off + m0 + lrow; if (garow > NPAIR-1) garow = NPAIR-1;
        a_src[i] = (const char*)h + (size_t)garow*(IDIM*2) + (lane & 7)*16;
    }
    const int base7 = (off + m0) & 7;

    const int wm = (wv >> 1) * 64, wn = (wv & 1) * 64;
    const int lr = lane & 15, lk = lane >> 4;

    const int NT = IDIM/64;   // 44 (even)
    int4v pkX0, pkX1, pkX2, pkX3, pkY0, pkY1, pkY2, pkY3;
    float sX, zX, sY, zY;

    ISSUE_A(0, 0);
    LOADB(pkX, sX, zX, 0);
    for (int kt = 0; kt < NT; kt += 2) {
        STEP1(kt,   0, 1, pkX, sX, zX, pkY, sY, zY);
        STEP1(kt+1, 1, 0, pkY, sY, zY, pkX, sX, zX);
    }
    __syncthreads();   // drain trailing (clamped) prefetch before epilogue/endpgm

#pragma unroll
    for (int mi = 0; mi < 4; ++mi)
#pragma unroll
        for (int nj = 0; nj < 4; ++nj) {
            f32x4 v = acc[mi][nj];
            int col = n0 + wn + nj*16 + lr;
#pragma unroll
            for (int r = 0; r < 4; ++r) {
                int row = wm + mi*16 + lk*4 + r;
                if (m0 + row < cnt) {
                    int p = meta[64 + off + m0 + row];
                    float w = tw[p];
                    yp[(size_t)p*DDIM + col] = v[r] * w;
                }
            }
        }
}

// ---------------- combine: out[t] = yp[2t] + yp[2t+1] ------------------------
__global__ void combine_kernel(const float* __restrict__ yp, float* __restrict__ out) {
    const int i = blockIdx.x * 256 + threadIdx.x;      // float4 index
    const int t = i >> 9, d = i & 511;
    const f32x4* a = (const f32x4*)yp;
    f32x4 va = a[(size_t)(t*2)*512 + d];
    f32x4 vb = a[(size_t)(t*2+1)*512 + d];
    ((f32x4*)out)[i] = va + vb;
}

extern "C" void kernel_launch(void* const* d_in, const int* in_sizes, int n_in,
                              void* d_out, int out_size, void* d_ws, size_t ws_size,
                              hipStream_t stream) {
    const float* x    = (const float*)d_in[0];
    const int*   ids  = (const int*)d_in[1];
    const float* tw   = (const float*)d_in[2];
    const int*   w13p = (const int*)d_in[3];
    const float* w13s = (const float*)d_in[4];
    const float* w13z = (const float*)d_in[5];
    const int*   w2p  = (const int*)d_in[6];
    const float* w2s  = (const float*)d_in[7];
    const float* w2z  = (const float*)d_in[8];
    float* out = (float*)d_out;

    char* ws = (char*)d_ws;
    int* meta = (int*)ws;
    unsigned short* Aall = (unsigned short*)(ws + OFF_A);
    unsigned short* gu   = (unsigned short*)(ws + OFF_GU);
    unsigned short* h    = (unsigned short*)(ws + OFF_H);
    float* yp            = (float*)(ws + OFF_YP);

    route_kernel<<<1, 256, 0, stream>>>(ids, meta);
    gather_kernel<<<NPAIR, 256, 0, stream>>>(x, meta, Aall);
    gemm1_kernel<<<dim3(GU_N/128, NPAIR/128, NE), 256, 0, stream>>>(Aall, w13p, w13s, w13z, meta, gu);
    act_kernel<<<NPAIR, 256, 0, stream>>>(gu, h);
    gemm2_kernel<<<dim3(DDIM/128, NPAIR/128, NE), 256, 0, stream>>>(h, w2p, w2s, w2z, tw, meta, yp);
    combine_kernel<<<(T_TOK*DDIM/4)/256, 256, 0, stream>>>(yp, out);
}